// Round 12
// baseline (620.713 us; speedup 1.0000x reference)
//
#include <hip/hip_runtime.h>
#include <math.h>

#define N_NODES 100000
#define N_EDGES 1600000
#define F_IN 64
#define SCAN_B 256
#define NB ((N_NODES + SCAN_B - 1) / SCAN_B)   // 391
#define L_BLOCKS 2048
#define L_WAVES (L_BLOCKS * 4)

// chunked-LDS histogram geometry
#define HIST_C 8                   // node chunks
#define HCHUNK 12500               // nodes per chunk (50 KB LDS); 8*12500 = N_NODES
#define HIST_S 32                  // edge slices
#define HSLICE (N_EDGES / HIST_S)  // 50000 edges per slice

static __device__ __forceinline__ ushort f2b(float f) {
    unsigned u = __float_as_uint(f);
    unsigned r = (u + 0x7fff + ((u >> 16) & 1)) >> 16;   // RNE
    return (ushort)r;
}
static __device__ __forceinline__ float bl(unsigned u) { return __uint_as_float(u << 16); }
static __device__ __forceinline__ float bh(unsigned u) { return __uint_as_float(u & 0xffff0000u); }
static __device__ __forceinline__ float rdlane(float v, int lane) {
    return __uint_as_float(__builtin_amdgcn_readlane(__float_as_uint(v), lane));
}

// x (f32) -> xb (bf16), 4 elems/thread
__global__ void k_cvt(const float4* __restrict__ x4, ushort4* __restrict__ xb4) {
    int i = blockIdx.x * blockDim.x + threadIdx.x;
    if (i < N_NODES * F_IN / 4) {
        float4 v = x4[i];
        ushort4 o;
        o.x = f2b(v.x); o.y = f2b(v.y); o.z = f2b(v.z); o.w = f2b(v.w);
        xb4[i] = o;
    }
}

// LDS-privatized histogram: block (c,s) bins slice s of keys[] into chunk c.
// No global atomics (memory-side atomic RMW was 100+ MB of HBM writes, R7/R11).
__global__ __launch_bounds__(256) void k_hist(const int* __restrict__ keys,
                                              int* __restrict__ partials) {
    __shared__ int h[HCHUNK];
    int c = blockIdx.x & (HIST_C - 1);
    int s = blockIdx.x >> 3;
    int t = threadIdx.x;
    for (int i = t; i < HCHUNK; i += 256) h[i] = 0;
    __syncthreads();
    int lo = c * HCHUNK;
    const int* k0 = keys + s * HSLICE;
    for (int i = t; i < HSLICE; i += 256) {
        int k = k0[i] - lo;
        if ((unsigned)k < HCHUNK) atomicAdd(&h[k], 1);   // LDS atomic
    }
    __syncthreads();
    int* p = partials + ((size_t)c * HIST_S + s) * HCHUNK;
    for (int i = t; i < HCHUNK; i += 256) p[i] = h[i];   // coalesced flush
}

// sum the 32 slice-partials per node -> deg[] (col pass; partials dead after)
__global__ void k_hreduce(const int* __restrict__ partials, int* __restrict__ deg) {
    int i = blockIdx.x * blockDim.x + threadIdx.x;
    if (i >= N_NODES) return;
    int c = i / HCHUNK, off = i - c * HCHUNK;
    const int* p = partials + (size_t)c * HIST_S * HCHUNK + off;
    int sum = 0;
#pragma unroll
    for (int s = 0; s < HIST_S; ++s) sum += p[s * HCHUNK];
    deg[i] = sum;
}

// row pass: deg[] = total, and partials <- exclusive prefix over slices (in place).
// pref[c][s][r] = #edges with row r in slices < s  (feeds atomic-free scatter).
__global__ void k_hredpref(int* __restrict__ partials, int* __restrict__ deg) {
    int i = blockIdx.x * blockDim.x + threadIdx.x;
    if (i >= N_NODES) return;
    int c = i / HCHUNK, off = i - c * HCHUNK;
    int* p = partials + (size_t)c * HIST_S * HCHUNK + off;
    int run = 0;
#pragma unroll
    for (int s = 0; s < HIST_S; ++s) {
        int v = p[s * HCHUNK];
        p[s * HCHUNK] = run;      // exclusive prefix
        run += v;
    }
    deg[i] = run;
}

// per-block exclusive scan of deg_out -> row_ptr (partial), block totals -> blockSums.
// Fused: inv_out/inv_in from degrees.
__global__ void k_scan1(const int* __restrict__ deg_out, const int* __restrict__ deg_in,
                        int* __restrict__ row_ptr, int* __restrict__ blockSums,
                        float* __restrict__ inv_out, float* __restrict__ inv_in) {
    __shared__ int s[SCAN_B];
    int t = threadIdx.x;
    int i = blockIdx.x * SCAN_B + t;
    int v = (i < N_NODES) ? deg_out[i] : 0;
    if (i < N_NODES) {
        int div = deg_in[i];
        inv_out[i] = v > 0 ? rsqrtf((float)v) : 0.0f;
        inv_in[i]  = div > 0 ? rsqrtf((float)div) : 0.0f;
    }
    s[t] = v;
    __syncthreads();
    for (int off = 1; off < SCAN_B; off <<= 1) {
        int add = (t >= off) ? s[t - off] : 0;
        __syncthreads();
        s[t] += add;
        __syncthreads();
    }
    if (i < N_NODES) row_ptr[i] = s[t] - v;  // exclusive
    if (t == SCAN_B - 1) blockSums[blockIdx.x] = s[t];
}

// parallel scan of 391 block sums in one 512-thread block
__global__ void k_scan2(int* __restrict__ blockSums) {
    __shared__ int s[512];
    int t = threadIdx.x;
    int v = (t < NB) ? blockSums[t] : 0;
    s[t] = v;
    __syncthreads();
    for (int off = 1; off < 512; off <<= 1) {
        int add = (t >= off) ? s[t - off] : 0;
        __syncthreads();
        s[t] += add;
        __syncthreads();
    }
    if (t < NB) blockSums[t] = s[t] - v;  // exclusive
}

__global__ void k_scan3(int* __restrict__ row_ptr, const int* __restrict__ blockSums) {
    int i = blockIdx.x * blockDim.x + threadIdx.x;
    if (i < N_NODES) {
        row_ptr[i] += blockSums[i / SCAN_B];
        if (i == 0) row_ptr[N_NODES] = N_EDGES;
    }
}

// Atomic-free CSR scatter: block (c,s) places slice-s edges whose row is in
// chunk c. LDS cursor seeded with row_ptr[r] + pref[c][s][r]; LDS atomics only.
__global__ __launch_bounds__(256) void k_scatter2(
    const int* __restrict__ row, const int* __restrict__ col,
    const int* __restrict__ row_ptr, const int* __restrict__ pref,
    const float* __restrict__ inv_in, int2* __restrict__ ew) {
    __shared__ int cur[HCHUNK];
    int c = blockIdx.x & (HIST_C - 1);
    int s = blockIdx.x >> 3;
    int t = threadIdx.x;
    int lo = c * HCHUNK;
    const int* pf = pref + ((size_t)c * HIST_S + s) * HCHUNK;
    for (int i = t; i < HCHUNK; i += 256) cur[i] = row_ptr[lo + i] + pf[i];
    __syncthreads();
    const int* r0 = row + s * HSLICE;
    const int* c0 = col + s * HSLICE;
    for (int i = t; i < HSLICE; i += 256) {
        int r = r0[i] - lo;
        if ((unsigned)r < HCHUNK) {
            int cc = c0[i];
            int slot = atomicAdd(&cur[r], 1);   // LDS atomic
            int2 v;
            v.x = cc;
            v.y = __float_as_int(inv_in[cc]);
            ew[slot] = v;
        }
    }
}

// Fused layer: y[r] = inv_out[r] * sum_e w_e * xb[col_e, :]; o = y @ W + b
// One wave per row (grid-stride). Gather: 8x8-lane groups, uint4 16B loads,
// 8 indep edge chains. GEMM: W in 64 VGPRs, y broadcast via v_readlane. No LDS.
template <int FOUT, bool STORE_F32, bool STORE_BF16, bool LSM>
__global__ __launch_bounds__(256, 4) void k_layer(
    const uint4* __restrict__ xb4,       // [N][8] uint4 = 64 bf16 per row
    const int2* __restrict__ ew,         // [E] {col, w}
    const int* __restrict__ row_ptr,
    const float* __restrict__ inv_out,
    const float* __restrict__ W,         // [64][FOUT]
    const float* __restrict__ bias,      // [FOUT]
    float* __restrict__ Yf32,            // [N][FOUT] or null
    ushort* __restrict__ Ybf) {          // [N][FOUT] bf16(relu(o)) or null
    int t = threadIdx.x;
    int lane = t & 63;
    int gw = (blockIdx.x * 256 + t) >> 6;
    int g = lane >> 3, fl = lane & 7;

    int j = (lane < FOUT) ? lane : 0;
    float Wreg[64];
#pragma unroll
    for (int k = 0; k < 64; ++k) Wreg[k] = W[k * FOUT + j];
    float bj = bias[j];

    for (int r = gw; r < N_NODES; r += L_WAVES) {
        float a0 = 0.f, a1 = 0.f, a2 = 0.f, a3 = 0.f;
        float a4 = 0.f, a5 = 0.f, a6 = 0.f, a7 = 0.f;
        int s = row_ptr[r], e = row_ptr[r + 1];
        for (int p = s + g; p < e; p += 8) {
            int2 cw = ew[p];
            float w = __int_as_float(cw.y);
            uint4 u = xb4[cw.x * 8 + fl];
            a0 = fmaf(w, bl(u.x), a0); a1 = fmaf(w, bh(u.x), a1);
            a2 = fmaf(w, bl(u.y), a2); a3 = fmaf(w, bh(u.y), a3);
            a4 = fmaf(w, bl(u.z), a4); a5 = fmaf(w, bh(u.z), a5);
            a6 = fmaf(w, bl(u.w), a6); a7 = fmaf(w, bh(u.w), a7);
        }
#pragma unroll
        for (int msk = 8; msk <= 32; msk <<= 1) {
            a0 += __shfl_xor(a0, msk); a1 += __shfl_xor(a1, msk);
            a2 += __shfl_xor(a2, msk); a3 += __shfl_xor(a3, msk);
            a4 += __shfl_xor(a4, msk); a5 += __shfl_xor(a5, msk);
            a6 += __shfl_xor(a6, msk); a7 += __shfl_xor(a7, msk);
        }
        float sc = inv_out[r];

        float acc = 0.f;
#pragma unroll
        for (int m = 0; m < 8; ++m) {
            acc = fmaf(rdlane(a0, m), Wreg[8 * m + 0], acc);
            acc = fmaf(rdlane(a1, m), Wreg[8 * m + 1], acc);
            acc = fmaf(rdlane(a2, m), Wreg[8 * m + 2], acc);
            acc = fmaf(rdlane(a3, m), Wreg[8 * m + 3], acc);
            acc = fmaf(rdlane(a4, m), Wreg[8 * m + 4], acc);
            acc = fmaf(rdlane(a5, m), Wreg[8 * m + 5], acc);
            acc = fmaf(rdlane(a6, m), Wreg[8 * m + 6], acc);
            acc = fmaf(rdlane(a7, m), Wreg[8 * m + 7], acc);
        }
        float o = fmaf(acc, sc, bj);

        if (LSM) {
            float v = (lane < FOUT) ? o : -INFINITY;
            float mx = v;
            for (int msk = 32; msk >= 1; msk >>= 1) mx = fmaxf(mx, __shfl_xor(mx, msk));
            float ex = (lane < FOUT) ? expf(o - mx) : 0.0f;
            float ssum = ex;
            for (int msk = 32; msk >= 1; msk >>= 1) ssum += __shfl_xor(ssum, msk);
            if (lane < FOUT) Yf32[(size_t)r * FOUT + lane] = o - mx - logf(ssum);
        } else {
            if (STORE_F32 && lane < FOUT) Yf32[(size_t)r * FOUT + lane] = o;
            if (STORE_BF16 && lane < FOUT) Ybf[(size_t)r * FOUT + lane] = f2b(fmaxf(o, 0.0f));
        }
    }
}

extern "C" void kernel_launch(void* const* d_in, const int* in_sizes, int n_in,
                              void* d_out, int out_size, void* d_ws, size_t ws_size,
                              hipStream_t stream) {
    const float* x   = (const float*)d_in[0];
    const int*   ei  = (const int*)d_in[1];
    const int*   row = ei;
    const int*   col = ei + N_EDGES;
    const float* W1s = (const float*)d_in[2];
    const float* b1s = (const float*)d_in[3];
    const float* W2s = (const float*)d_in[6];
    const float* b2s = (const float*)d_in[7];
    const float* Wos = (const float*)d_in[10];
    const float* bos = (const float*)d_in[11];

    float* out_h   = (float*)d_out;                       // [N,64]
    float* out_lsm = out_h + (size_t)N_NODES * 64;        // [N,40]

    char* ws = (char*)d_ws;
    size_t off = 0;
    auto alloc = [&](size_t bytes) -> void* {
        void* p = ws + off;
        off += (bytes + 255) / 256 * 256;
        return p;
    };
    int*   degs      = (int*)alloc((size_t)2 * N_NODES * 4);   // deg_out | deg_in
    int*   deg_out   = degs;
    int*   deg_in    = degs + N_NODES;
    float* inv_out   = (float*)alloc((size_t)N_NODES * 4);
    float* inv_in    = (float*)alloc((size_t)N_NODES * 4);
    int*   row_ptr   = (int*)alloc(((size_t)N_NODES + 1) * 4);
    int*   blockSums = (int*)alloc((size_t)NB * 4);
    int2*  ewbuf     = (int2*)alloc((size_t)N_EDGES * 8);            // 12.8 MB
    ushort* xb       = (ushort*)alloc((size_t)N_NODES * F_IN * 2);   // 12.8 MB (reused for hb)
    ushort* x0b      = (ushort*)alloc((size_t)N_NODES * F_IN * 2);   // 12.8 MB
    ushort* hb       = xb;   // xb dead after layer 1
    // partials/pref [C][S][HCHUNK] = 12.8 MB, aliased onto x0b: last read is
    // k_scatter2 (before L1); x0b first written by L1.
    int*   partials  = (int*)x0b;

    const int TB = 256;
    int gN = (N_NODES + TB - 1) / TB;        // 391

    k_cvt<<<(N_NODES * F_IN / 4 + TB - 1) / TB, TB, 0, stream>>>((const float4*)x, (ushort4*)xb);
    // col pass first (its partials die after deg_in); row pass's prefix
    // survives until k_scatter2.
    k_hist<<<HIST_C * HIST_S, 256, 0, stream>>>(col, partials);
    k_hreduce<<<gN, TB, 0, stream>>>(partials, deg_in);
    k_hist<<<HIST_C * HIST_S, 256, 0, stream>>>(row, partials);
    k_hredpref<<<gN, TB, 0, stream>>>(partials, deg_out);
    k_scan1<<<NB, SCAN_B, 0, stream>>>(deg_out, deg_in, row_ptr, blockSums, inv_out, inv_in);
    k_scan2<<<1, 512, 0, stream>>>(blockSums);
    k_scan3<<<gN, TB, 0, stream>>>(row_ptr, blockSums);
    k_scatter2<<<HIST_C * HIST_S, 256, 0, stream>>>(row, col, row_ptr, partials, inv_in, ewbuf);

    // L1: x -> x0b (bf16 relu'd only)
    k_layer<64, false, true, false><<<L_BLOCKS, 256, 0, stream>>>(
        (const uint4*)xb, ewbuf, row_ptr, inv_out, W1s, b1s, nullptr, x0b);
    // L2: x0b -> h (f32 out) + hb (bf16 relu'd)
    k_layer<64, true, true, false><<<L_BLOCKS, 256, 0, stream>>>(
        (const uint4*)x0b, ewbuf, row_ptr, inv_out, W2s, b2s, out_h, hb);
    // L3: hb -> log_softmax (f32 out)
    k_layer<40, true, false, true><<<L_BLOCKS, 256, 0, stream>>>(
        (const uint4*)hb, ewbuf, row_ptr, inv_out, Wos, bos, out_lsm, nullptr);
}

// Round 14
// 444.852 us; speedup vs baseline: 1.3953x; 1.3953x over previous
//
#include <hip/hip_runtime.h>
#include <math.h>

#define N_NODES 100000
#define N_EDGES 1600000
#define F_IN 64
#define SCAN_B 256
#define NB ((N_NODES + SCAN_B - 1) / SCAN_B)   // 391
#define L_BLOCKS 2048
#define L_WAVES (L_BLOCKS * 4)

// chunked-LDS histogram geometry
#define HIST_C 8                   // node chunks
#define HCHUNK 12500               // nodes per chunk (50 KB LDS); 8*12500 = N_NODES
#define HIST_S 32                  // edge slices
#define HSLICE (N_EDGES / HIST_S)  // 50000 edges per slice

static __device__ __forceinline__ ushort f2b(float f) {
    unsigned u = __float_as_uint(f);
    unsigned r = (u + 0x7fff + ((u >> 16) & 1)) >> 16;   // RNE
    return (ushort)r;
}
static __device__ __forceinline__ float bl(unsigned u) { return __uint_as_float(u << 16); }
static __device__ __forceinline__ float bh(unsigned u) { return __uint_as_float(u & 0xffff0000u); }
static __device__ __forceinline__ float rdlane(float v, int lane) {
    return __uint_as_float(__builtin_amdgcn_readlane(__float_as_uint(v), lane));
}

// x (f32) -> xb (bf16), 4 elems/thread
__global__ void k_cvt(const float4* __restrict__ x4, ushort4* __restrict__ xb4) {
    int i = blockIdx.x * blockDim.x + threadIdx.x;
    if (i < N_NODES * F_IN / 4) {
        float4 v = x4[i];
        ushort4 o;
        o.x = f2b(v.x); o.y = f2b(v.y); o.z = f2b(v.z); o.w = f2b(v.w);
        xb4[i] = o;
    }
}

// Packed dual LDS histogram: block (c,s) bins slice s's ROW keys into the low
// halfword and COL keys into the high halfword of one 50 KB LDS array.
// Max count per (slice,node) = 50000 < 2^16, so no carry crosses halves.
// 1024 threads; no global atomics (memory-side RMW cost measured R7/R11).
__global__ __launch_bounds__(1024) void k_hist2(const int* __restrict__ row,
                                                const int* __restrict__ col,
                                                int* __restrict__ prow,
                                                int* __restrict__ pcol) {
    __shared__ unsigned h[HCHUNK];
    int c = blockIdx.x & (HIST_C - 1);
    int s = blockIdx.x >> 3;
    int t = threadIdx.x;
    for (int i = t; i < HCHUNK; i += 1024) h[i] = 0u;
    __syncthreads();
    int lo = c * HCHUNK;
    const int* r0 = row + s * HSLICE;
    const int* c0 = col + s * HSLICE;
    for (int i = t; i < HSLICE; i += 1024) {
        int rk = r0[i] - lo;
        if ((unsigned)rk < HCHUNK) atomicAdd(&h[rk], 1u);        // row -> low
        int ck = c0[i] - lo;
        if ((unsigned)ck < HCHUNK) atomicAdd(&h[ck], 1u << 16);  // col -> high
    }
    __syncthreads();
    int* pr = prow + ((size_t)c * HIST_S + s) * HCHUNK;
    int* pc = pcol + ((size_t)c * HIST_S + s) * HCHUNK;
    for (int i = t; i < HCHUNK; i += 1024) {
        unsigned v = h[i];
        pr[i] = (int)(v & 0xffffu);
        pc[i] = (int)(v >> 16);
    }
}

// Fused: deg_in = sum(pcol), deg_out = sum(prow), and prow <- exclusive
// prefix over slices in place (pref[c][s][r] = #row-r edges in slices < s).
__global__ void k_hred2(int* __restrict__ prow, const int* __restrict__ pcol,
                        int* __restrict__ deg_out, int* __restrict__ deg_in) {
    int i = blockIdx.x * blockDim.x + threadIdx.x;
    if (i >= N_NODES) return;
    int c = i / HCHUNK, off = i - c * HCHUNK;
    int* pr = prow + (size_t)c * HIST_S * HCHUNK + off;
    const int* pc = pcol + (size_t)c * HIST_S * HCHUNK + off;
    int run = 0, sumc = 0;
#pragma unroll
    for (int s = 0; s < HIST_S; ++s) {
        int v = pr[s * HCHUNK];
        pr[s * HCHUNK] = run;     // exclusive prefix
        run += v;
        sumc += pc[s * HCHUNK];
    }
    deg_out[i] = run;
    deg_in[i] = sumc;
}

// per-block exclusive scan of deg_out -> row_ptr (partial), block totals -> blockSums.
// Fused: inv_out/inv_in from degrees.
__global__ void k_scan1(const int* __restrict__ deg_out, const int* __restrict__ deg_in,
                        int* __restrict__ row_ptr, int* __restrict__ blockSums,
                        float* __restrict__ inv_out, float* __restrict__ inv_in) {
    __shared__ int s[SCAN_B];
    int t = threadIdx.x;
    int i = blockIdx.x * SCAN_B + t;
    int v = (i < N_NODES) ? deg_out[i] : 0;
    if (i < N_NODES) {
        int div = deg_in[i];
        inv_out[i] = v > 0 ? rsqrtf((float)v) : 0.0f;
        inv_in[i]  = div > 0 ? rsqrtf((float)div) : 0.0f;
    }
    s[t] = v;
    __syncthreads();
    for (int off = 1; off < SCAN_B; off <<= 1) {
        int add = (t >= off) ? s[t - off] : 0;
        __syncthreads();
        s[t] += add;
        __syncthreads();
    }
    if (i < N_NODES) row_ptr[i] = s[t] - v;  // exclusive
    if (t == SCAN_B - 1) blockSums[blockIdx.x] = s[t];
}

// parallel scan of 391 block sums in one 512-thread block
__global__ void k_scan2(int* __restrict__ blockSums) {
    __shared__ int s[512];
    int t = threadIdx.x;
    int v = (t < NB) ? blockSums[t] : 0;
    s[t] = v;
    __syncthreads();
    for (int off = 1; off < 512; off <<= 1) {
        int add = (t >= off) ? s[t - off] : 0;
        __syncthreads();
        s[t] += add;
        __syncthreads();
    }
    if (t < NB) blockSums[t] = s[t] - v;  // exclusive
}

__global__ void k_scan3(int* __restrict__ row_ptr, const int* __restrict__ blockSums) {
    int i = blockIdx.x * blockDim.x + threadIdx.x;
    if (i < N_NODES) {
        row_ptr[i] += blockSums[i / SCAN_B];
        if (i == 0) row_ptr[N_NODES] = N_EDGES;
    }
}

// Atomic-free CSR scatter: block (c,s) places slice-s edges whose row is in
// chunk c. LDS cursor seeded with row_ptr[r] + pref[c][s][r]; LDS atomics only.
// 1024 threads (R12's 256t/1-block-per-CU was 10.6% occupancy, latency-bound).
__global__ __launch_bounds__(1024) void k_scatter2(
    const int* __restrict__ row, const int* __restrict__ col,
    const int* __restrict__ row_ptr, const int* __restrict__ pref,
    const float* __restrict__ inv_in, int2* __restrict__ ew) {
    __shared__ int cur[HCHUNK];
    int c = blockIdx.x & (HIST_C - 1);
    int s = blockIdx.x >> 3;
    int t = threadIdx.x;
    int lo = c * HCHUNK;
    const int* pf = pref + ((size_t)c * HIST_S + s) * HCHUNK;
    for (int i = t; i < HCHUNK; i += 1024) cur[i] = row_ptr[lo + i] + pf[i];
    __syncthreads();
    const int* r0 = row + s * HSLICE;
    const int* c0 = col + s * HSLICE;
    for (int i = t; i < HSLICE; i += 1024) {
        int r = r0[i] - lo;
        if ((unsigned)r < HCHUNK) {
            int cc = c0[i];
            int slot = atomicAdd(&cur[r], 1);   // LDS atomic
            int2 v;
            v.x = cc;
            v.y = __float_as_int(inv_in[cc]);
            ew[slot] = v;
        }
    }
}

// Fused layer: y[r] = inv_out[r] * sum_e w_e * xb[col_e, :]; o = y @ W + b
// One wave per row (grid-stride). Gather: 8x8-lane groups, uint4 16B loads,
// 8 indep edge chains. GEMM: W in 64 VGPRs, y broadcast via v_readlane. No LDS.
template <int FOUT, bool STORE_F32, bool STORE_BF16, bool LSM>
__global__ __launch_bounds__(256, 4) void k_layer(
    const uint4* __restrict__ xb4,       // [N][8] uint4 = 64 bf16 per row
    const int2* __restrict__ ew,         // [E] {col, w}
    const int* __restrict__ row_ptr,
    const float* __restrict__ inv_out,
    const float* __restrict__ W,         // [64][FOUT]
    const float* __restrict__ bias,      // [FOUT]
    float* __restrict__ Yf32,            // [N][FOUT] or null
    ushort* __restrict__ Ybf) {          // [N][FOUT] bf16(relu(o)) or null
    int t = threadIdx.x;
    int lane = t & 63;
    int gw = (blockIdx.x * 256 + t) >> 6;
    int g = lane >> 3, fl = lane & 7;

    int j = (lane < FOUT) ? lane : 0;
    float Wreg[64];
#pragma unroll
    for (int k = 0; k < 64; ++k) Wreg[k] = W[k * FOUT + j];
    float bj = bias[j];

    for (int r = gw; r < N_NODES; r += L_WAVES) {
        float a0 = 0.f, a1 = 0.f, a2 = 0.f, a3 = 0.f;
        float a4 = 0.f, a5 = 0.f, a6 = 0.f, a7 = 0.f;
        int s = row_ptr[r], e = row_ptr[r + 1];
        for (int p = s + g; p < e; p += 8) {
            int2 cw = ew[p];
            float w = __int_as_float(cw.y);
            uint4 u = xb4[cw.x * 8 + fl];
            a0 = fmaf(w, bl(u.x), a0); a1 = fmaf(w, bh(u.x), a1);
            a2 = fmaf(w, bl(u.y), a2); a3 = fmaf(w, bh(u.y), a3);
            a4 = fmaf(w, bl(u.z), a4); a5 = fmaf(w, bh(u.z), a5);
            a6 = fmaf(w, bl(u.w), a6); a7 = fmaf(w, bh(u.w), a7);
        }
#pragma unroll
        for (int msk = 8; msk <= 32; msk <<= 1) {
            a0 += __shfl_xor(a0, msk); a1 += __shfl_xor(a1, msk);
            a2 += __shfl_xor(a2, msk); a3 += __shfl_xor(a3, msk);
            a4 += __shfl_xor(a4, msk); a5 += __shfl_xor(a5, msk);
            a6 += __shfl_xor(a6, msk); a7 += __shfl_xor(a7, msk);
        }
        float sc = inv_out[r];

        float acc = 0.f;
#pragma unroll
        for (int m = 0; m < 8; ++m) {
            acc = fmaf(rdlane(a0, m), Wreg[8 * m + 0], acc);
            acc = fmaf(rdlane(a1, m), Wreg[8 * m + 1], acc);
            acc = fmaf(rdlane(a2, m), Wreg[8 * m + 2], acc);
            acc = fmaf(rdlane(a3, m), Wreg[8 * m + 3], acc);
            acc = fmaf(rdlane(a4, m), Wreg[8 * m + 4], acc);
            acc = fmaf(rdlane(a5, m), Wreg[8 * m + 5], acc);
            acc = fmaf(rdlane(a6, m), Wreg[8 * m + 6], acc);
            acc = fmaf(rdlane(a7, m), Wreg[8 * m + 7], acc);
        }
        float o = fmaf(acc, sc, bj);

        if (LSM) {
            float v = (lane < FOUT) ? o : -INFINITY;
            float mx = v;
            for (int msk = 32; msk >= 1; msk >>= 1) mx = fmaxf(mx, __shfl_xor(mx, msk));
            float ex = (lane < FOUT) ? expf(o - mx) : 0.0f;
            float ssum = ex;
            for (int msk = 32; msk >= 1; msk >>= 1) ssum += __shfl_xor(ssum, msk);
            if (lane < FOUT) Yf32[(size_t)r * FOUT + lane] = o - mx - logf(ssum);
        } else {
            if (STORE_F32 && lane < FOUT) Yf32[(size_t)r * FOUT + lane] = o;
            if (STORE_BF16 && lane < FOUT) Ybf[(size_t)r * FOUT + lane] = f2b(fmaxf(o, 0.0f));
        }
    }
}

extern "C" void kernel_launch(void* const* d_in, const int* in_sizes, int n_in,
                              void* d_out, int out_size, void* d_ws, size_t ws_size,
                              hipStream_t stream) {
    const float* x   = (const float*)d_in[0];
    const int*   ei  = (const int*)d_in[1];
    const int*   row = ei;
    const int*   col = ei + N_EDGES;
    const float* W1s = (const float*)d_in[2];
    const float* b1s = (const float*)d_in[3];
    const float* W2s = (const float*)d_in[6];
    const float* b2s = (const float*)d_in[7];
    const float* Wos = (const float*)d_in[10];
    const float* bos = (const float*)d_in[11];

    float* out_h   = (float*)d_out;                       // [N,64]
    float* out_lsm = out_h + (size_t)N_NODES * 64;        // [N,40]

    char* ws = (char*)d_ws;
    size_t off = 0;
    auto alloc = [&](size_t bytes) -> void* {
        void* p = ws + off;
        off += (bytes + 255) / 256 * 256;
        return p;
    };
    int*   degs      = (int*)alloc((size_t)2 * N_NODES * 4);   // deg_out | deg_in
    int*   deg_out   = degs;
    int*   deg_in    = degs + N_NODES;
    float* inv_out   = (float*)alloc((size_t)N_NODES * 4);
    float* inv_in    = (float*)alloc((size_t)N_NODES * 4);
    int*   row_ptr   = (int*)alloc(((size_t)N_NODES + 1) * 4);
    int*   blockSums = (int*)alloc((size_t)NB * 4);
    int2*  ewbuf     = (int2*)alloc((size_t)N_EDGES * 8);            // 12.8 MB
    ushort* xb       = (ushort*)alloc((size_t)N_NODES * F_IN * 2);   // 12.8 MB (reused for hb)
    ushort* x0b      = (ushort*)alloc((size_t)N_NODES * F_IN * 2);   // 12.8 MB
    ushort* hb       = xb;   // xb dead after layer 1
    // prow (later pref) [C][S][HCHUNK] = 12.8 MB aliased onto x0b (last read:
    // k_scatter2, before L1 writes x0b). pcol = 12.8 MB aliased onto ewbuf
    // (last read: k_hred2, before k_scatter2 writes ewbuf).
    int*   prow      = (int*)x0b;
    int*   pcol     = (int*)ewbuf;

    const int TB = 256;
    int gN = (N_NODES + TB - 1) / TB;        // 391

    k_cvt<<<(N_NODES * F_IN / 4 + TB - 1) / TB, TB, 0, stream>>>((const float4*)x, (ushort4*)xb);
    k_hist2<<<HIST_C * HIST_S, 1024, 0, stream>>>(row, col, prow, pcol);
    k_hred2<<<gN, TB, 0, stream>>>(prow, pcol, deg_out, deg_in);
    k_scan1<<<NB, SCAN_B, 0, stream>>>(deg_out, deg_in, row_ptr, blockSums, inv_out, inv_in);
    k_scan2<<<1, 512, 0, stream>>>(blockSums);
    k_scan3<<<gN, TB, 0, stream>>>(row_ptr, blockSums);
    k_scatter2<<<HIST_C * HIST_S, 1024, 0, stream>>>(row, col, row_ptr, prow, inv_in, ewbuf);

    // L1: x -> x0b (bf16 relu'd only)
    k_layer<64, false, true, false><<<L_BLOCKS, 256, 0, stream>>>(
        (const uint4*)xb, ewbuf, row_ptr, inv_out, W1s, b1s, nullptr, x0b);
    // L2: x0b -> h (f32 out) + hb (bf16 relu'd)
    k_layer<64, true, true, false><<<L_BLOCKS, 256, 0, stream>>>(
        (const uint4*)x0b, ewbuf, row_ptr, inv_out, W2s, b2s, out_h, hb);
    // L3: hb -> log_softmax (f32 out)
    k_layer<40, true, false, true><<<L_BLOCKS, 256, 0, stream>>>(
        (const uint4*)hb, ewbuf, row_ptr, inv_out, Wos, bos, out_lsm, nullptr);
}